// Round 4
// baseline (52.388 us; speedup 1.0000x reference)
//
#include <hip/hip_runtime.h>
#include <hip/hip_bf16.h>

#define BATCH 4096
#define FEAT  64
#define LW    64
#define KH    5
#define KW    9
#define RH    5
#define PADL  4
#define CUT   5    // positions p>=41 (h==4, ww>=5) are compile-time masked out
#define NPOS  41
#define NW    8    // waves per block

typedef __attribute__((ext_vector_type(8))) short bf16x8;
typedef __attribute__((ext_vector_type(4))) float f32x4;

__device__ __forceinline__ short f2bf(float x) {
    union { float f; unsigned u; } v; v.f = x;
    unsigned r = v.u + 0x7FFFu + ((v.u >> 16) & 1u);  // RNE
    return (short)(r >> 16);
}

__device__ __forceinline__ bf16x8 cvt8(f32x4 x0, f32x4 x1) {
    bf16x8 a;
    a[0]=f2bf(x0[0]); a[1]=f2bf(x0[1]); a[2]=f2bf(x0[2]); a[3]=f2bf(x0[3]);
    a[4]=f2bf(x1[0]); a[5]=f2bf(x1[1]); a[6]=f2bf(x1[2]); a[7]=f2bf(x1[3]);
    return a;
}

// One wave's position chunk. Weights are loaded f32->bf16 into REGISTERS once
// (all masking folded into fragment zeroing), then the R2-proven main loop:
// per position 4 direct f32x4 A-loads + 8 MFMAs. All array indices static.
template<int W>
__device__ __forceinline__ void chunk(
    const float* __restrict__ inputs, const float* __restrict__ cache,
    const float* __restrict__ Wgl,
    int r0, int index_w, bool upd, bool shift, int n, int g,
    f32x4 acc[4])
{
    constexpr int P0 = (NPOS * W) / NW;
    constexpr int P1 = (NPOS * (W + 1)) / NW;
    constexpr int NP = P1 - P0;

    bf16x8 bfr[NP][4][2];

    // ---- weight phase: L2-resident f32 W -> bf16 fragments in registers ----
    #pragma unroll
    for (int pi = 0; pi < NP; ++pi) {
        const int p = P0 + pi;
        const int h = p / KW, ww = p % KW;              // compile-time
        const bool is_input = upd && (h == KH - 1) && (ww == PADL);
        const int col = index_w - PADL + ww;
        const bool zero = (!is_input && (col < 0 || col >= LW))
                       || (!is_input && shift && h == KH - 1);
        const float* wp = Wgl + p * 4096;
        if (zero) {
            #pragma unroll
            for (int ft = 0; ft < 4; ++ft)
                #pragma unroll
                for (int hf = 0; hf < 2; ++hf)
                    bfr[pi][ft][hf] = bf16x8{0,0,0,0,0,0,0,0};
        } else {
            #pragma unroll
            for (int ft = 0; ft < 4; ++ft) {
                #pragma unroll
                for (int hf = 0; hf < 2; ++hf) {
                    bf16x8 bf;
                    #pragma unroll
                    for (int j = 0; j < 8; ++j)
                        bf[j] = f2bf(wp[(hf * 32 + g * 8 + j) * 64 + ft * 16 + n]);
                    bfr[pi][ft][hf] = bf;
                }
            }
        }
    }

    // ---- main loop: A direct loads + MFMA (R2 structure, B from registers) --
    const long b = r0 + n;
    const float* crow  = cache  + b * (RH * LW * FEAT);
    const float* inrow = inputs + b * FEAT;
    const int k0 = g * 8;

    #pragma unroll
    for (int pi = 0; pi < NP; ++pi) {
        const int p = P0 + pi;
        const int h = p / KW, ww = p % KW;              // compile-time
        int col  = index_w - PADL + ww;
        int colc = min(max(col, 0), LW - 1);            // clamp; OOB => zero frag
        int hh   = shift ? min(h + 1, RH - 1) : h;      // clamped (zero frag row)
        const float* aptr = crow + (hh * LW + colc) * FEAT;
        if (h == KH - 1 && ww == PADL) {                // compile-time check
            if (upd) aptr = inrow;                      // uniform runtime select
        }
        f32x4 x0 = *(const f32x4*)(aptr + k0);
        f32x4 x1 = *(const f32x4*)(aptr + k0 + 4);
        f32x4 x2 = *(const f32x4*)(aptr + 32 + k0);
        f32x4 x3 = *(const f32x4*)(aptr + 32 + k0 + 4);
        bf16x8 a0 = cvt8(x0, x1);
        bf16x8 a1 = cvt8(x2, x3);
        #pragma unroll
        for (int ft = 0; ft < 4; ++ft) {
            acc[ft] = __builtin_amdgcn_mfma_f32_16x16x32_bf16(a0, bfr[pi][ft][0], acc[ft], 0, 0, 0);
            acc[ft] = __builtin_amdgcn_mfma_f32_16x16x32_bf16(a1, bfr[pi][ft][1], acc[ft], 0, 0, 0);
        }
    }
}

__global__ __launch_bounds__(512, 2) void conv_kernel(
    const float* __restrict__ inputs, const float* __restrict__ cache,
    const float* __restrict__ Wgl, const float* __restrict__ bias,
    const int* __restrict__ idxp, float* __restrict__ out)
{
    __shared__ float Lacc[NW][16][65];   // 33 KB K-split partials

    const int t    = threadIdx.x;
    const int lane = t & 63;
    const int wv   = t >> 6;             // 0..7 = K-chunk id
    const int n    = lane & 15;          // A row offset (m) and B col offset (f)
    const int g    = lane >> 4;          // k-group
    const int r0   = blockIdx.x * 16;

    const int index = idxp[0];
    int index_w = ((index % LW) + LW) % LW;
    const bool upd   = index >= 0;
    const bool shift = upd && (index_w == 0);

    f32x4 acc[4] = {{0,0,0,0},{0,0,0,0},{0,0,0,0},{0,0,0,0}};

    switch (wv) {
        case 0: chunk<0>(inputs, cache, Wgl, r0, index_w, upd, shift, n, g, acc); break;
        case 1: chunk<1>(inputs, cache, Wgl, r0, index_w, upd, shift, n, g, acc); break;
        case 2: chunk<2>(inputs, cache, Wgl, r0, index_w, upd, shift, n, g, acc); break;
        case 3: chunk<3>(inputs, cache, Wgl, r0, index_w, upd, shift, n, g, acc); break;
        case 4: chunk<4>(inputs, cache, Wgl, r0, index_w, upd, shift, n, g, acc); break;
        case 5: chunk<5>(inputs, cache, Wgl, r0, index_w, upd, shift, n, g, acc); break;
        case 6: chunk<6>(inputs, cache, Wgl, r0, index_w, upd, shift, n, g, acc); break;
        default: chunk<7>(inputs, cache, Wgl, r0, index_w, upd, shift, n, g, acc); break;
    }

    // D layout: col f = ft*16+n, row m = g*4+i
    #pragma unroll
    for (int ft = 0; ft < 4; ++ft)
        #pragma unroll
        for (int i = 0; i < 4; ++i)
            Lacc[wv][g * 4 + i][ft * 16 + n] = acc[ft][i];

    __syncthreads();

    // Reduce over the 8 waves: thread t -> f = lane, rows m = wv and wv+8
    const int f = lane;
    #pragma unroll
    for (int half = 0; half < 2; ++half) {
        const int m = wv + half * 8;
        float s = bias[f];
        #pragma unroll
        for (int w2 = 0; w2 < NW; ++w2) s += Lacc[w2][m][f];
        out[(long)(r0 + m) * FEAT + f] = s;
    }
}

extern "C" void kernel_launch(void* const* d_in, const int* in_sizes, int n_in,
                              void* d_out, int out_size, void* d_ws, size_t ws_size,
                              hipStream_t stream) {
    const float* inputs = (const float*)d_in[0];
    const float* cache  = (const float*)d_in[1];
    const float* kern   = (const float*)d_in[2];
    const float* bias   = (const float*)d_in[3];
    const int*   idx    = (const int*)d_in[4];
    float* out = (float*)d_out;

    conv_kernel<<<BATCH / 16, 512, 0, stream>>>(inputs, cache, kern, bias, idx, out);
}

// Round 5
// 16.229 us; speedup vs baseline: 3.2281x; 3.2281x over previous
//
#include <hip/hip_runtime.h>
#include <hip/hip_bf16.h>

#define BATCH 4096
#define FEAT  64
#define LW    64
#define KH    5
#define KW    9
#define RH    5
#define PADL  4
#define NPOS  41   // p = h*KW+ww, 0..40; p>=41 (h==4, ww>=5) compile-time masked
#define NW    16   // waves per block (K-split)

typedef __attribute__((ext_vector_type(8))) short bf16x8;
typedef __attribute__((ext_vector_type(4))) float f32x4;

__device__ __forceinline__ bf16x8 cvt8(f32x4 x0, f32x4 x1) {
    union { bf16x8 v; __hip_bfloat162 h[4]; } u;
    u.h[0] = __float22bfloat162_rn(float2{x0[0], x0[1]});
    u.h[1] = __float22bfloat162_rn(float2{x0[2], x0[3]});
    u.h[2] = __float22bfloat162_rn(float2{x1[0], x1[1]});
    u.h[3] = __float22bfloat162_rn(float2{x1[2], x1[3]});
    return u.v;
}

__device__ __forceinline__ bf16x8 cvt8s(const float* w) {
    union { bf16x8 v; __hip_bfloat162 h[4]; } u;
    u.h[0] = __float22bfloat162_rn(float2{w[0], w[1]});
    u.h[1] = __float22bfloat162_rn(float2{w[2], w[3]});
    u.h[2] = __float22bfloat162_rn(float2{w[4], w[5]});
    u.h[3] = __float22bfloat162_rn(float2{w[6], w[7]});
    return u.v;
}

// One wave's position chunk. B-fragments are built TRANSIENTLY in the inner
// loop from f32 W (L2/L3-resident, imm-offset scalar loads) — no resident
// weight registers (R4 lesson). Zero-weight positions skip entirely.
template<int W>
__device__ __forceinline__ void chunk(
    const float* __restrict__ inputs, const float* __restrict__ cache,
    const float* __restrict__ Wgl,
    int r0, int index_w, bool upd, bool shift, int n, int g,
    f32x4 acc[4])
{
    constexpr int P0 = (NPOS * W) / NW;
    constexpr int P1 = (NPOS * (W + 1)) / NW;

    const long b = r0 + n;
    const float* crow  = cache  + b * (RH * LW * FEAT);
    const float* inrow = inputs + b * FEAT;
    const int k0 = g * 8;

    #pragma unroll
    for (int p = P0; p < P1; ++p) {
        const int h = p / KW, ww = p % KW;               // compile-time
        const int col = index_w - PADL + ww;             // wave-uniform
        const bool is_input = upd && (h == KH - 1) && (ww == PADL);
        const bool zero = (!is_input && (col < 0 || col >= LW))
                       || (!is_input && shift && h == KH - 1);
        if (zero) continue;                              // wave-uniform skip

        // when !zero && !is_input: col in [0,LW); when shift: h<KH-1 so hh<=RH-1
        const int hh = shift ? h + 1 : h;
        const float* aptr = is_input ? inrow
                                     : crow + (hh * LW + col) * FEAT;

        f32x4 x0 = *(const f32x4*)(aptr + k0);
        f32x4 x1 = *(const f32x4*)(aptr + k0 + 4);
        f32x4 x2 = *(const f32x4*)(aptr + 32 + k0);
        f32x4 x3 = *(const f32x4*)(aptr + 32 + k0 + 4);
        bf16x8 a0 = cvt8(x0, x1);
        bf16x8 a1 = cvt8(x2, x3);

        // B element (j, hf, ft) = W[p][hf*32 + g*8 + j][ft*16 + n]
        const float* wb0 = Wgl + p * 4096 + k0 * 64 + n;   // hf=0 base
        const float* wb1 = wb0 + 32 * 64;                  // hf=1 base
        #pragma unroll
        for (int ft = 0; ft < 4; ++ft) {
            float w0[8], w1[8];
            #pragma unroll
            for (int j = 0; j < 8; ++j) {
                w0[j] = wb0[j * 64 + ft * 16];             // imm offsets
                w1[j] = wb1[j * 64 + ft * 16];
            }
            bf16x8 b0 = cvt8s(w0);
            bf16x8 b1 = cvt8s(w1);
            acc[ft] = __builtin_amdgcn_mfma_f32_16x16x32_bf16(a0, b0, acc[ft], 0, 0, 0);
            acc[ft] = __builtin_amdgcn_mfma_f32_16x16x32_bf16(a1, b1, acc[ft], 0, 0, 0);
        }
    }
}

__global__ __launch_bounds__(1024) void conv_kernel(
    const float* __restrict__ inputs, const float* __restrict__ cache,
    const float* __restrict__ Wgl, const float* __restrict__ bias,
    const int* __restrict__ idxp, float* __restrict__ out)
{
    __shared__ float Lacc[NW][16][65];   // 66.5 KB K-split partials

    const int t    = threadIdx.x;
    const int lane = t & 63;
    const int wv   = t >> 6;             // 0..15 = K-chunk id
    const int n    = lane & 15;          // A row offset (m) and B col offset (f)
    const int g    = lane >> 4;          // k-group
    const int r0   = blockIdx.x * 16;

    const int index = idxp[0];
    int index_w = ((index % LW) + LW) % LW;
    const bool upd   = index >= 0;
    const bool shift = upd && (index_w == 0);

    f32x4 acc[4] = {{0,0,0,0},{0,0,0,0},{0,0,0,0},{0,0,0,0}};

    switch (wv) {
        case 0:  chunk<0 >(inputs, cache, Wgl, r0, index_w, upd, shift, n, g, acc); break;
        case 1:  chunk<1 >(inputs, cache, Wgl, r0, index_w, upd, shift, n, g, acc); break;
        case 2:  chunk<2 >(inputs, cache, Wgl, r0, index_w, upd, shift, n, g, acc); break;
        case 3:  chunk<3 >(inputs, cache, Wgl, r0, index_w, upd, shift, n, g, acc); break;
        case 4:  chunk<4 >(inputs, cache, Wgl, r0, index_w, upd, shift, n, g, acc); break;
        case 5:  chunk<5 >(inputs, cache, Wgl, r0, index_w, upd, shift, n, g, acc); break;
        case 6:  chunk<6 >(inputs, cache, Wgl, r0, index_w, upd, shift, n, g, acc); break;
        case 7:  chunk<7 >(inputs, cache, Wgl, r0, index_w, upd, shift, n, g, acc); break;
        case 8:  chunk<8 >(inputs, cache, Wgl, r0, index_w, upd, shift, n, g, acc); break;
        case 9:  chunk<9 >(inputs, cache, Wgl, r0, index_w, upd, shift, n, g, acc); break;
        case 10: chunk<10>(inputs, cache, Wgl, r0, index_w, upd, shift, n, g, acc); break;
        case 11: chunk<11>(inputs, cache, Wgl, r0, index_w, upd, shift, n, g, acc); break;
        case 12: chunk<12>(inputs, cache, Wgl, r0, index_w, upd, shift, n, g, acc); break;
        case 13: chunk<13>(inputs, cache, Wgl, r0, index_w, upd, shift, n, g, acc); break;
        case 14: chunk<14>(inputs, cache, Wgl, r0, index_w, upd, shift, n, g, acc); break;
        default: chunk<15>(inputs, cache, Wgl, r0, index_w, upd, shift, n, g, acc); break;
    }

    // D layout: col f = ft*16+n, row m = g*4+i
    #pragma unroll
    for (int ft = 0; ft < 4; ++ft)
        #pragma unroll
        for (int i = 0; i < 4; ++i)
            Lacc[wv][g * 4 + i][ft * 16 + n] = acc[ft][i];

    __syncthreads();

    // Reduce over the 16 K-chunks: thread t -> (m = wv, f = lane)
    const int m = wv;
    const int f = lane;
    float s = bias[f];
    #pragma unroll
    for (int w2 = 0; w2 < NW; ++w2) s += Lacc[w2][m][f];
    out[(long)(r0 + m) * FEAT + f] = s;
}

extern "C" void kernel_launch(void* const* d_in, const int* in_sizes, int n_in,
                              void* d_out, int out_size, void* d_ws, size_t ws_size,
                              hipStream_t stream) {
    const float* inputs = (const float*)d_in[0];
    const float* cache  = (const float*)d_in[1];
    const float* kern   = (const float*)d_in[2];
    const float* bias   = (const float*)d_in[3];
    const int*   idx    = (const int*)d_in[4];
    float* out = (float*)d_out;

    conv_kernel<<<BATCH / 16, 1024, 0, stream>>>(inputs, cache, kern, bias, idx, out);
}